// Round 2
// baseline (4489.907 us; speedup 1.0000x reference)
//
#include <hip/hip_runtime.h>
#include <math.h>

#define B_  256
#define H_  200
#define N_  64
#define D_  640
#define DT_ 256
#define NH_ 10
#define HD_ 64

__device__ __forceinline__ float wave_reduce_sum(float v) {
    #pragma unroll
    for (int m = 32; m > 0; m >>= 1) v += __shfl_xor(v, m);
    return v;
}
__device__ __forceinline__ float wave_reduce_max(float v) {
    #pragma unroll
    for (int m = 32; m > 0; m >>= 1) v = fmaxf(v, __shfl_xor(v, m));
    return v;
}

// Y[row, d] = sum_k X[row, k] * W[d, k] + bias[d]   (K = DT_ = 256, Dout = 640)
// 8 rows per block, 256 threads, 3 d-slots per thread.
__global__ __launch_bounds__(256) void proj_kernel(
    const float* __restrict__ X, const float* __restrict__ W,
    const float* __restrict__ bias, float* __restrict__ Y)
{
    __shared__ float xs[8][DT_];
    const int t = threadIdx.x;
    const long row0 = (long)blockIdx.x * 8;
    #pragma unroll
    for (int r = 0; r < 8; ++r) xs[r][t] = X[(row0 + r) * DT_ + t];
    __syncthreads();

    float acc[8][3];
    #pragma unroll
    for (int r = 0; r < 8; ++r) { acc[r][0] = 0.f; acc[r][1] = 0.f; acc[r][2] = 0.f; }

    const int d0 = t, d1 = t + 256;
    const int d2 = (t < 128) ? (t + 512) : t;   // safe fallback addr for t>=128
    const float4* W4 = (const float4*)W;

    for (int k4 = 0; k4 < DT_ / 4; ++k4) {
        float4 w0 = W4[(long)d0 * (DT_ / 4) + k4];
        float4 w1 = W4[(long)d1 * (DT_ / 4) + k4];
        float4 w2 = W4[(long)d2 * (DT_ / 4) + k4];
        #pragma unroll
        for (int r = 0; r < 8; ++r) {
            float4 xv = ((const float4*)xs[r])[k4];
            acc[r][0] += xv.x * w0.x + xv.y * w0.y + xv.z * w0.z + xv.w * w0.w;
            acc[r][1] += xv.x * w1.x + xv.y * w1.y + xv.z * w1.z + xv.w * w1.w;
            acc[r][2] += xv.x * w2.x + xv.y * w2.y + xv.z * w2.z + xv.w * w2.w;
        }
    }
    const float b0 = bias[d0], b1 = bias[d1], b2 = bias[d2];
    #pragma unroll
    for (int r = 0; r < 8; ++r) {
        float* yr = Y + (row0 + r) * D_;
        yr[d0] = acc[r][0] + b0;
        yr[d1] = acc[r][1] + b1;
        if (t < 128) yr[d2] = acc[r][2] + b2;
    }
}

// Per block: one b, 8 candidate rows n0..n0+7.
// For each h: scores over m=0..199, softmax over m, accumulate sum over h.
__global__ __launch_bounds__(256) void attn_kernel(
    const float* __restrict__ Qf, const float* __restrict__ Kf,
    float* __restrict__ Ssum)
{
    __shared__ float q[8][D_];
    __shared__ float sm[8][H_];
    __shared__ float ssl[8][H_];
    __shared__ float dnl[8];
    const int t = threadIdx.x;
    const int lane = t & 63, wave = t >> 6;
    const int b = blockIdx.x >> 3;
    const int n0 = (blockIdx.x & 7) * 8;

    for (int idx = t; idx < 8 * D_; idx += 256)
        ((float*)q)[idx] = Qf[((long)(b * N_ + n0)) * D_ + idx];
    for (int idx = t; idx < 8 * H_; idx += 256) ((float*)ssl)[idx] = 0.f;
    __syncthreads();

    const float inv_scale = 0.0395284707521047f;  // 1/sqrt(640)

    for (int h = 0; h < NH_; ++h) {
        if (t < H_) {
            float acc[8];
            #pragma unroll
            for (int r = 0; r < 8; ++r) acc[r] = 0.f;
            const float4* K4 = (const float4*)(Kf + ((long)(b * H_ + t)) * D_ + h * HD_);
            #pragma unroll
            for (int k4 = 0; k4 < HD_ / 4; ++k4) {
                float4 kv = K4[k4];
                #pragma unroll
                for (int r = 0; r < 8; ++r) {
                    float4 qv = ((const float4*)(&q[r][h * HD_]))[k4];
                    acc[r] += qv.x * kv.x + qv.y * kv.y + qv.z * kv.z + qv.w * kv.w;
                }
            }
            #pragma unroll
            for (int r = 0; r < 8; ++r) sm[r][t] = acc[r] * inv_scale;
        }
        __syncthreads();
        // softmax over m (200) for each of the 8 rows; wave w handles rows w, w+4
        for (int rr = wave; rr < 8; rr += 4) {
            float v0 = sm[rr][lane];
            float v1 = sm[rr][lane + 64];
            float v2 = sm[rr][lane + 128];
            const bool has3 = lane < (H_ - 192);
            float v3 = has3 ? sm[rr][lane + 192] : -INFINITY;
            float mx = fmaxf(fmaxf(v0, v1), fmaxf(v2, v3));
            mx = wave_reduce_max(mx);
            float e0 = __expf(v0 - mx), e1 = __expf(v1 - mx), e2 = __expf(v2 - mx);
            float e3 = has3 ? __expf(v3 - mx) : 0.f;
            sm[rr][lane] = e0; sm[rr][lane + 64] = e1; sm[rr][lane + 128] = e2;
            if (has3) sm[rr][lane + 192] = e3;
            float s = wave_reduce_sum(e0 + e1 + e2 + e3);
            if (lane == 0) dnl[rr] = s;
        }
        __syncthreads();
        if (t < H_) {
            #pragma unroll
            for (int r = 0; r < 8; ++r) ssl[r][t] += sm[r][t] * (1.0f / dnl[r]);
        }
        __syncthreads();
    }
    if (t < H_) {
        #pragma unroll
        for (int r = 0; r < 8; ++r)
            Ssum[((long)(b * N_ + n0 + r)) * H_ + t] = ssl[r][t];
    }
}

// Per block: one b. query-norm softmax -> agg over n -> softmax over m -> aw.
__global__ __launch_bounds__(256) void agg_kernel(
    const float* __restrict__ Qf, const float* __restrict__ Ssum,
    float* __restrict__ aw, float* __restrict__ out_tail)
{
    __shared__ float qn[N_];
    __shared__ float qwl[N_];
    __shared__ float ag[256];
    __shared__ float red[2];
    const int t = threadIdx.x, lane = t & 63, wave = t >> 6;
    const int b = blockIdx.x;

    // row norms of Qf[b, n, :]
    for (int n = wave; n < N_; n += 4) {
        float ss = 0.f;
        #pragma unroll
        for (int i = 0; i < D_ / 64; ++i) {
            float v = Qf[((long)(b * N_ + n)) * D_ + lane + 64 * i];
            ss += v * v;
        }
        ss = wave_reduce_sum(ss);
        if (lane == 0) qn[n] = sqrtf(ss);
    }
    __syncthreads();
    // softmax over the 64 candidates
    if (wave == 0) {
        float v = qn[lane];
        float mx = wave_reduce_max(v);
        float e = __expf(v - mx);
        float s = wave_reduce_sum(e);
        qwl[lane] = e / s;
    }
    __syncthreads();
    // agg[m] = sum_n Ssum[b,n,m] * qw[n]
    if (t < H_) {
        float a = 0.f;
        for (int n = 0; n < N_; ++n)
            a += Ssum[((long)(b * N_ + n)) * H_ + t] * qwl[n];
        ag[t] = a;
    }
    __syncthreads();
    if (wave == 0) {
        float v0 = ag[lane], v1 = ag[lane + 64], v2 = ag[lane + 128];
        const bool has3 = lane < (H_ - 192);
        float v3 = has3 ? ag[lane + 192] : -INFINITY;
        float mx = wave_reduce_max(fmaxf(fmaxf(v0, v1), fmaxf(v2, v3)));
        float s = __expf(v0 - mx) + __expf(v1 - mx) + __expf(v2 - mx)
                + (has3 ? __expf(v3 - mx) : 0.f);
        s = wave_reduce_sum(s);
        if (lane == 0) { red[0] = mx; red[1] = s; }
    }
    __syncthreads();
    if (t < H_) {
        float v = __expf(ag[t] - red[0]) / red[1];
        aw[b * H_ + t] = v;
        out_tail[b * H_ + t] = v;
    }
}

// Per block: 8 rows of [B*H]. weighted = aw*clicked; z = weighted@Wg.T + bg;
// gate = sigmoid(z); out = LN(gate*weighted + (1-gate)*clicked).
__global__ __launch_bounds__(256) void out_kernel(
    const float* __restrict__ clicked, const float* __restrict__ aw,
    const float* __restrict__ Wg, const float* __restrict__ bg,
    const float* __restrict__ gamma, const float* __restrict__ beta,
    float* __restrict__ out)
{
    __shared__ float cl[8][D_];
    __shared__ float wo[8][D_];
    __shared__ float awl[8];
    const int t = threadIdx.x, lane = t & 63, wave = t >> 6;
    const long row0 = (long)blockIdx.x * 8;

    if (t < 8) awl[t] = aw[row0 + t];
    for (int idx = t; idx < 8 * D_; idx += 256)
        ((float*)cl)[idx] = clicked[row0 * D_ + idx];
    __syncthreads();
    for (int idx = t; idx < 8 * D_; idx += 256)
        ((float*)wo)[idx] = awl[idx / D_] * ((float*)cl)[idx];
    __syncthreads();

    float acc[8][3];
    #pragma unroll
    for (int r = 0; r < 8; ++r) { acc[r][0] = 0.f; acc[r][1] = 0.f; acc[r][2] = 0.f; }

    const int d0 = t, d1 = t + 256;
    const int d2 = (t < 128) ? (t + 512) : t;
    const float4* G4 = (const float4*)Wg;

    for (int k4 = 0; k4 < D_ / 4; ++k4) {
        float4 g0 = G4[(long)d0 * (D_ / 4) + k4];
        float4 g1 = G4[(long)d1 * (D_ / 4) + k4];
        float4 g2 = G4[(long)d2 * (D_ / 4) + k4];
        #pragma unroll
        for (int r = 0; r < 8; ++r) {
            float4 wv = ((const float4*)wo[r])[k4];
            acc[r][0] += wv.x * g0.x + wv.y * g0.y + wv.z * g0.z + wv.w * g0.w;
            acc[r][1] += wv.x * g1.x + wv.y * g1.y + wv.z * g1.z + wv.w * g1.w;
            acc[r][2] += wv.x * g2.x + wv.y * g2.y + wv.z * g2.z + wv.w * g2.w;
        }
    }

    // Compute blended values into REGISTERS only (reads of wo/cl), so no
    // thread writes wo while another wave is still reading it in its GEMM
    // loop. (Round-1 bug: write-after-read race across waves.)
    const float b0 = bg[d0], b1 = bg[d1], b2 = bg[d2];
    float blend[8][3];
    #pragma unroll
    for (int r = 0; r < 8; ++r) {
        {
            float z = acc[r][0] + b0;
            float g = 1.f / (1.f + __expf(-z));
            blend[r][0] = g * wo[r][d0] + (1.f - g) * cl[r][d0];
        }
        {
            float z = acc[r][1] + b1;
            float g = 1.f / (1.f + __expf(-z));
            blend[r][1] = g * wo[r][d1] + (1.f - g) * cl[r][d1];
        }
        if (t < 128) {
            float z = acc[r][2] + b2;
            float g = 1.f / (1.f + __expf(-z));
            blend[r][2] = g * wo[r][d2] + (1.f - g) * cl[r][d2];
        }
    }
    __syncthreads();   // all GEMM reads of wo complete before any write
    #pragma unroll
    for (int r = 0; r < 8; ++r) {
        wo[r][d0] = blend[r][0];
        wo[r][d1] = blend[r][1];
        if (t < 128) wo[r][d2] = blend[r][2];
    }
    __syncthreads();

    // LayerNorm: wave w handles rows 2w and 2w+1
    #pragma unroll
    for (int rr = 0; rr < 2; ++rr) {
        const int r = wave * 2 + rr;
        float s = 0.f, sq = 0.f;
        #pragma unroll
        for (int i = 0; i < D_ / 64; ++i) {
            float v = wo[r][lane + 64 * i];
            s += v; sq += v * v;
        }
        s = wave_reduce_sum(s);
        sq = wave_reduce_sum(sq);
        const float mu = s * (1.f / D_);
        const float var = sq * (1.f / D_) - mu * mu;
        const float rinv = 1.0f / sqrtf(var + 1e-5f);
        #pragma unroll
        for (int i = 0; i < D_ / 64; ++i) {
            const int d = lane + 64 * i;
            float v = wo[r][d];
            out[(row0 + r) * D_ + d] = (v - mu) * rinv * gamma[d] + beta[d];
        }
    }
}

extern "C" void kernel_launch(void* const* d_in, const int* in_sizes, int n_in,
                              void* d_out, int out_size, void* d_ws, size_t ws_size,
                              hipStream_t stream) {
    const float* clicked_news   = (const float*)d_in[0];   // [B,H,D]
    const float* clicked_topics = (const float*)d_in[1];   // [B,H,Dt]
    const float* cand_topics    = (const float*)d_in[2];   // [B,N,Dt]
    const float* Wq = (const float*)d_in[3];
    const float* bq = (const float*)d_in[4];
    const float* Wk = (const float*)d_in[5];
    const float* bk = (const float*)d_in[6];
    // d_in[7], d_in[8] = Wv, bv: dead code w.r.t. outputs
    const float* Wg = (const float*)d_in[9];
    const float* bg = (const float*)d_in[10];
    const float* ln_gamma = (const float*)d_in[11];
    const float* ln_beta  = (const float*)d_in[12];

    float* out = (float*)d_out;
    float* ws  = (float*)d_ws;

    // workspace layout (floats)
    float* Qf   = ws;                                   // B*N*D   = 10,485,760
    float* Ssum = ws + (long)B_ * N_ * D_;              // B*N*H   =  3,276,800
    float* aw   = Ssum + (long)B_ * N_ * H_;            // B*H     =     51,200
    // Kf lives in d_out[0 : B*H*D] -- read by attn_kernel, overwritten by out_kernel
    float* Kf = out;
    float* out_tail = out + (long)B_ * H_ * D_;         // attn_weights_agg

    proj_kernel<<<(B_ * N_) / 8, 256, 0, stream>>>(cand_topics, Wq, bq, Qf);
    proj_kernel<<<(B_ * H_) / 8, 256, 0, stream>>>(clicked_topics, Wk, bk, Kf);
    attn_kernel<<<B_ * (N_ / 8), 256, 0, stream>>>(Qf, Kf, Ssum);
    agg_kernel<<<B_, 256, 0, stream>>>(Qf, Ssum, aw, out_tail);
    out_kernel<<<(B_ * H_) / 8, 256, 0, stream>>>(clicked_news, aw, Wg, bg,
                                                  ln_gamma, ln_beta, out);
}

// Round 3
// 825.409 us; speedup vs baseline: 5.4396x; 5.4396x over previous
//
#include <hip/hip_runtime.h>
#include <math.h>

#define B_  256
#define H_  200
#define N_  64
#define D_  640
#define DT_ 256
#define NH_ 10
#define HD_ 64

typedef __attribute__((ext_vector_type(8))) short bf16x8;
typedef __attribute__((ext_vector_type(4))) float f32x4;

__device__ __forceinline__ float wave_reduce_sum(float v) {
    #pragma unroll
    for (int m = 32; m > 0; m >>= 1) v += __shfl_xor(v, m);
    return v;
}
__device__ __forceinline__ float wave_reduce_max(float v) {
    #pragma unroll
    for (int m = 32; m > 0; m >>= 1) v = fmaxf(v, __shfl_xor(v, m));
    return v;
}
__device__ __forceinline__ short f2bf(float x) {   // RNE bf16
    unsigned u = __float_as_uint(x);
    unsigned r = (u + 0x7fffu + ((u >> 16) & 1u)) >> 16;
    return (short)r;
}
__device__ __forceinline__ float bf2f(short s) {
    return __uint_as_float(((unsigned)(unsigned short)s) << 16);
}
// LDS XOR swizzle (G4): spread row-major rows (stride % 128B == 0) across banks
#define SWZ(row, byte) ((byte) ^ (((row) & 7) << 4))

// fp32 -> bf16 bit conversion, grid-stride
__global__ __launch_bounds__(256) void convert_w(
    const float* __restrict__ src, short* __restrict__ dst, int n)
{
    for (int i = blockIdx.x * 256 + threadIdx.x; i < n; i += gridDim.x * 256)
        dst[i] = f2bf(src[i]);
}

// Y[row, d] = sum_k X[row,k] * W[d,k] + bias[d]; K=256, Dout=640.
// 32 rows/block, 4 waves = (wm 2) x (wn 2 col-halves of 320).
__global__ __launch_bounds__(256) void proj_mfma(
    const float* __restrict__ X, const short* __restrict__ Wb,
    const float* __restrict__ bias, float* __restrict__ Y)
{
    __shared__ short A_lds[32 * DT_];   // 16 KB, swizzled bf16
    const int t = threadIdx.x;
    const int lane = t & 63, w = t >> 6;
    const int wm = w >> 1, wn = w & 1;
    const int r16 = lane & 15, g = lane >> 4;
    const long row0 = (long)blockIdx.x * 32;

    // stage X -> bf16 LDS
    {
        const float4* X4 = (const float4*)(X + row0 * DT_);
        for (int i = t; i < 32 * (DT_ / 4); i += 256) {
            float4 v = X4[i];
            int row = i / (DT_ / 4);
            int k4  = i % (DT_ / 4);
            short4 s;
            s.x = f2bf(v.x); s.y = f2bf(v.y); s.z = f2bf(v.z); s.w = f2bf(v.w);
            *(short4*)((char*)A_lds + SWZ(row, row * (DT_ * 2) + k4 * 8)) = s;
        }
    }
    __syncthreads();

    const int arow = wm * 16 + r16;
    for (int ct = 0; ct < 5; ++ct) {
        const int cb = wn * 320 + ct * 64;
        f32x4 acc0 = {0.f,0.f,0.f,0.f}, acc1 = acc0, acc2 = acc0, acc3 = acc0;
        const short* Wbase = Wb + (long)(cb + r16) * DT_ + g * 8;
        #pragma unroll
        for (int kc = 0; kc < DT_ / 32; ++kc) {
            bf16x8 a = *(const bf16x8*)((const char*)A_lds +
                        SWZ(arow, arow * (DT_ * 2) + kc * 64 + g * 16));
            bf16x8 b0 = *(const bf16x8*)(Wbase + 0 * 16 * DT_ + kc * 32);
            bf16x8 b1 = *(const bf16x8*)(Wbase + 1 * 16 * DT_ + kc * 32);
            bf16x8 b2 = *(const bf16x8*)(Wbase + 2 * 16 * DT_ + kc * 32);
            bf16x8 b3 = *(const bf16x8*)(Wbase + 3 * 16 * DT_ + kc * 32);
            acc0 = __builtin_amdgcn_mfma_f32_16x16x32_bf16(a, b0, acc0, 0, 0, 0);
            acc1 = __builtin_amdgcn_mfma_f32_16x16x32_bf16(a, b1, acc1, 0, 0, 0);
            acc2 = __builtin_amdgcn_mfma_f32_16x16x32_bf16(a, b2, acc2, 0, 0, 0);
            acc3 = __builtin_amdgcn_mfma_f32_16x16x32_bf16(a, b3, acc3, 0, 0, 0);
        }
        // C/D layout: col = lane&15, row = (lane>>4)*4 + i
        #pragma unroll
        for (int f = 0; f < 4; ++f) {
            const f32x4 acc = (f == 0) ? acc0 : (f == 1) ? acc1 : (f == 2) ? acc2 : acc3;
            const int col = cb + f * 16 + r16;
            const float bv = bias[col];
            #pragma unroll
            for (int i = 0; i < 4; ++i)
                Y[(row0 + wm * 16 + g * 4 + i) * (long)D_ + col] = acc[i] + bv;
        }
    }
}

// gate GEMM + blend + LayerNorm, 32 rows/block. K = 640.
__global__ __launch_bounds__(256) void out_mfma(
    const float* __restrict__ clicked, const float* __restrict__ aw,
    const short* __restrict__ Wgb, const float* __restrict__ bg,
    const float* __restrict__ gamma, const float* __restrict__ beta,
    float* __restrict__ out)
{
    __shared__ short A_lds[32 * D_];   // 40 KB, swizzled weighted bf16
    __shared__ short z_lds[32 * D_];   // 40 KB, plain layout z bf16
    const int t = threadIdx.x;
    const int lane = t & 63, w = t >> 6;
    const int wm = w >> 1, wn = w & 1;
    const int r16 = lane & 15, g = lane >> 4;
    const long row0 = (long)blockIdx.x * 32;

    // stage weighted = aw[row] * clicked[row,:] -> bf16 LDS
    {
        const float4* C4 = (const float4*)(clicked + row0 * D_);
        for (int i = t; i < 32 * (D_ / 4); i += 256) {
            int row = i / (D_ / 4);
            int k4  = i % (D_ / 4);
            float a = aw[row0 + row];
            float4 v = C4[i];
            short4 s;
            s.x = f2bf(v.x * a); s.y = f2bf(v.y * a);
            s.z = f2bf(v.z * a); s.w = f2bf(v.w * a);
            *(short4*)((char*)A_lds + SWZ(row, row * (D_ * 2) + k4 * 8)) = s;
        }
    }
    __syncthreads();

    const int arow = wm * 16 + r16;
    for (int ct = 0; ct < 5; ++ct) {
        const int cb = wn * 320 + ct * 64;
        f32x4 acc0 = {0.f,0.f,0.f,0.f}, acc1 = acc0, acc2 = acc0, acc3 = acc0;
        const short* Wbase = Wgb + (long)(cb + r16) * D_ + g * 8;
        #pragma unroll
        for (int kc = 0; kc < D_ / 32; ++kc) {
            bf16x8 a = *(const bf16x8*)((const char*)A_lds +
                        SWZ(arow, arow * (D_ * 2) + kc * 64 + g * 16));
            bf16x8 b0 = *(const bf16x8*)(Wbase + 0 * 16 * D_ + kc * 32);
            bf16x8 b1 = *(const bf16x8*)(Wbase + 1 * 16 * D_ + kc * 32);
            bf16x8 b2 = *(const bf16x8*)(Wbase + 2 * 16 * D_ + kc * 32);
            bf16x8 b3 = *(const bf16x8*)(Wbase + 3 * 16 * D_ + kc * 32);
            acc0 = __builtin_amdgcn_mfma_f32_16x16x32_bf16(a, b0, acc0, 0, 0, 0);
            acc1 = __builtin_amdgcn_mfma_f32_16x16x32_bf16(a, b1, acc1, 0, 0, 0);
            acc2 = __builtin_amdgcn_mfma_f32_16x16x32_bf16(a, b2, acc2, 0, 0, 0);
            acc3 = __builtin_amdgcn_mfma_f32_16x16x32_bf16(a, b3, acc3, 0, 0, 0);
        }
        #pragma unroll
        for (int f = 0; f < 4; ++f) {
            const f32x4 acc = (f == 0) ? acc0 : (f == 1) ? acc1 : (f == 2) ? acc2 : acc3;
            const int col = cb + f * 16 + r16;
            const float bv = bg[col];
            #pragma unroll
            for (int i = 0; i < 4; ++i)
                z_lds[(wm * 16 + g * 4 + i) * D_ + col] = f2bf(acc[i] + bv);
        }
    }
    __syncthreads();

    // blend + LayerNorm: wave w handles rows w*8 .. w*8+7
    for (int rr = 0; rr < 8; ++rr) {
        const int r = w * 8 + rr;
        const long base = (row0 + r) * (long)D_;
        const float aww = aw[row0 + r];
        float ov[10];
        float s = 0.f, sq = 0.f;
        #pragma unroll
        for (int i = 0; i < 10; ++i) {
            const int c = lane + 64 * i;
            float cl = clicked[base + c];
            float z  = bf2f(z_lds[r * D_ + c]);
            float gt = 1.f / (1.f + __expf(-z));
            float o  = gt * (aww * cl) + (1.f - gt) * cl;
            ov[i] = o; s += o; sq += o * o;
        }
        s  = wave_reduce_sum(s);
        sq = wave_reduce_sum(sq);
        const float mu  = s * (1.f / D_);
        const float var = sq * (1.f / D_) - mu * mu;
        const float rinv = 1.0f / sqrtf(var + 1e-5f);
        #pragma unroll
        for (int i = 0; i < 10; ++i) {
            const int c = lane + 64 * i;
            out[base + c] = (ov[i] - mu) * rinv * gamma[c] + beta[c];
        }
    }
}

// Per block: one b, 8 candidate rows n0..n0+7.
__global__ __launch_bounds__(256) void attn_kernel(
    const float* __restrict__ Qf, const float* __restrict__ Kf,
    float* __restrict__ Ssum)
{
    __shared__ float q[8][D_];
    __shared__ float sm[8][H_];
    __shared__ float ssl[8][H_];
    __shared__ float dnl[8];
    const int t = threadIdx.x;
    const int lane = t & 63, wave = t >> 6;
    const int b = blockIdx.x >> 3;
    const int n0 = (blockIdx.x & 7) * 8;

    for (int idx = t; idx < 8 * D_; idx += 256)
        ((float*)q)[idx] = Qf[((long)(b * N_ + n0)) * D_ + idx];
    for (int idx = t; idx < 8 * H_; idx += 256) ((float*)ssl)[idx] = 0.f;
    __syncthreads();

    const float inv_scale = 0.0395284707521047f;  // 1/sqrt(640)

    for (int h = 0; h < NH_; ++h) {
        if (t < H_) {
            float acc[8];
            #pragma unroll
            for (int r = 0; r < 8; ++r) acc[r] = 0.f;
            const float4* K4 = (const float4*)(Kf + ((long)(b * H_ + t)) * D_ + h * HD_);
            #pragma unroll
            for (int k4 = 0; k4 < HD_ / 4; ++k4) {
                float4 kv = K4[k4];
                #pragma unroll
                for (int r = 0; r < 8; ++r) {
                    float4 qv = ((const float4*)(&q[r][h * HD_]))[k4];
                    acc[r] += qv.x * kv.x + qv.y * kv.y + qv.z * kv.z + qv.w * kv.w;
                }
            }
            #pragma unroll
            for (int r = 0; r < 8; ++r) sm[r][t] = acc[r] * inv_scale;
        }
        __syncthreads();
        for (int rr = wave; rr < 8; rr += 4) {
            float v0 = sm[rr][lane];
            float v1 = sm[rr][lane + 64];
            float v2 = sm[rr][lane + 128];
            const bool has3 = lane < (H_ - 192);
            float v3 = has3 ? sm[rr][lane + 192] : -INFINITY;
            float mx = fmaxf(fmaxf(v0, v1), fmaxf(v2, v3));
            mx = wave_reduce_max(mx);
            float e0 = __expf(v0 - mx), e1 = __expf(v1 - mx), e2 = __expf(v2 - mx);
            float e3 = has3 ? __expf(v3 - mx) : 0.f;
            sm[rr][lane] = e0; sm[rr][lane + 64] = e1; sm[rr][lane + 128] = e2;
            if (has3) sm[rr][lane + 192] = e3;
            float s = wave_reduce_sum(e0 + e1 + e2 + e3);
            if (lane == 0) dnl[rr] = s;
        }
        __syncthreads();
        if (t < H_) {
            #pragma unroll
            for (int r = 0; r < 8; ++r) ssl[r][t] += sm[r][t] * (1.0f / dnl[r]);
        }
        __syncthreads();
    }
    if (t < H_) {
        #pragma unroll
        for (int r = 0; r < 8; ++r)
            Ssum[((long)(b * N_ + n0 + r)) * H_ + t] = ssl[r][t];
    }
}

// Per block: one b. query-norm softmax -> agg over n -> softmax over m -> aw.
__global__ __launch_bounds__(256) void agg_kernel(
    const float* __restrict__ Qf, const float* __restrict__ Ssum,
    float* __restrict__ aw, float* __restrict__ out_tail)
{
    __shared__ float qn[N_];
    __shared__ float qwl[N_];
    __shared__ float ag[256];
    __shared__ float red[2];
    const int t = threadIdx.x, lane = t & 63, wave = t >> 6;
    const int b = blockIdx.x;

    for (int n = wave; n < N_; n += 4) {
        float ss = 0.f;
        #pragma unroll
        for (int i = 0; i < D_ / 64; ++i) {
            float v = Qf[((long)(b * N_ + n)) * D_ + lane + 64 * i];
            ss += v * v;
        }
        ss = wave_reduce_sum(ss);
        if (lane == 0) qn[n] = sqrtf(ss);
    }
    __syncthreads();
    if (wave == 0) {
        float v = qn[lane];
        float mx = wave_reduce_max(v);
        float e = __expf(v - mx);
        float s = wave_reduce_sum(e);
        qwl[lane] = e / s;
    }
    __syncthreads();
    if (t < H_) {
        float a = 0.f;
        for (int n = 0; n < N_; ++n)
            a += Ssum[((long)(b * N_ + n)) * H_ + t] * qwl[n];
        ag[t] = a;
    }
    __syncthreads();
    if (wave == 0) {
        float v0 = ag[lane], v1 = ag[lane + 64], v2 = ag[lane + 128];
        const bool has3 = lane < (H_ - 192);
        float v3 = has3 ? ag[lane + 192] : -INFINITY;
        float mx = wave_reduce_max(fmaxf(fmaxf(v0, v1), fmaxf(v2, v3)));
        float s = __expf(v0 - mx) + __expf(v1 - mx) + __expf(v2 - mx)
                + (has3 ? __expf(v3 - mx) : 0.f);
        s = wave_reduce_sum(s);
        if (lane == 0) { red[0] = mx; red[1] = s; }
    }
    __syncthreads();
    if (t < H_) {
        float v = __expf(ag[t] - red[0]) / red[1];
        aw[b * H_ + t] = v;
        out_tail[b * H_ + t] = v;
    }
}

extern "C" void kernel_launch(void* const* d_in, const int* in_sizes, int n_in,
                              void* d_out, int out_size, void* d_ws, size_t ws_size,
                              hipStream_t stream) {
    const float* clicked_news   = (const float*)d_in[0];   // [B,H,D]
    const float* clicked_topics = (const float*)d_in[1];   // [B,H,Dt]
    const float* cand_topics    = (const float*)d_in[2];   // [B,N,Dt]
    const float* Wq = (const float*)d_in[3];
    const float* bq = (const float*)d_in[4];
    const float* Wk = (const float*)d_in[5];
    const float* bk = (const float*)d_in[6];
    // d_in[7], d_in[8] = Wv, bv: dead code w.r.t. outputs
    const float* Wg = (const float*)d_in[9];
    const float* bg = (const float*)d_in[10];
    const float* ln_gamma = (const float*)d_in[11];
    const float* ln_beta  = (const float*)d_in[12];

    float* out = (float*)d_out;
    float* ws  = (float*)d_ws;

    // workspace layout
    float* Qf   = ws;                                   // B*N*D   = 10,485,760 f
    float* Ssum = ws + (long)B_ * N_ * D_;              // B*N*H   =  3,276,800 f
    float* aw   = Ssum + (long)B_ * N_ * H_;            // B*H     =     51,200 f
    short* Wq_b = (short*)(aw + (long)B_ * H_);         // 640*256 shorts
    short* Wk_b = Wq_b + (long)D_ * DT_;
    short* Wg_b = Wk_b + (long)D_ * DT_;                // 640*640 shorts
    // Kf lives in d_out[0 : B*H*D] -- read by attn_kernel, overwritten by out_mfma
    float* Kf = out;
    float* out_tail = out + (long)B_ * H_ * D_;         // attn_weights_agg

    convert_w<<<128, 256, 0, stream>>>(Wq, Wq_b, D_ * DT_);
    convert_w<<<128, 256, 0, stream>>>(Wk, Wk_b, D_ * DT_);
    convert_w<<<256, 256, 0, stream>>>(Wg, Wg_b, D_ * D_);

    proj_mfma<<<(B_ * N_) / 32, 256, 0, stream>>>(cand_topics, Wq_b, bq, Qf);
    proj_mfma<<<(B_ * H_) / 32, 256, 0, stream>>>(clicked_topics, Wk_b, bk, Kf);
    attn_kernel<<<B_ * (N_ / 8), 256, 0, stream>>>(Qf, Kf, Ssum);
    agg_kernel<<<B_, 256, 0, stream>>>(Qf, Ssum, aw, out_tail);
    out_mfma<<<(B_ * H_) / 32, 256, 0, stream>>>(clicked_news, aw, Wg_b, bg,
                                                 ln_gamma, ln_beta, out);
}

// Round 4
// 713.468 us; speedup vs baseline: 6.2931x; 1.1569x over previous
//
#include <hip/hip_runtime.h>
#include <math.h>

#define B_  256
#define H_  200
#define N_  64
#define D_  640
#define DT_ 256
#define NH_ 10
#define HD_ 64
#define MT_ 13   // 13 m-tiles of 16 cover 208 >= 200

typedef __attribute__((ext_vector_type(8))) short bf16x8;
typedef __attribute__((ext_vector_type(4))) float f32x4;

__device__ __forceinline__ float wave_reduce_sum(float v) {
    #pragma unroll
    for (int m = 32; m > 0; m >>= 1) v += __shfl_xor(v, m);
    return v;
}
__device__ __forceinline__ float wave_reduce_max(float v) {
    #pragma unroll
    for (int m = 32; m > 0; m >>= 1) v = fmaxf(v, __shfl_xor(v, m));
    return v;
}
__device__ __forceinline__ float red16_sum(float v) {   // reduce over lane&15 group
    #pragma unroll
    for (int m = 1; m < 16; m <<= 1) v += __shfl_xor(v, m);
    return v;
}
__device__ __forceinline__ float red16_max(float v) {
    #pragma unroll
    for (int m = 1; m < 16; m <<= 1) v = fmaxf(v, __shfl_xor(v, m));
    return v;
}
__device__ __forceinline__ short f2bf(float x) {   // RNE bf16
    unsigned u = __float_as_uint(x);
    unsigned r = (u + 0x7fffu + ((u >> 16) & 1u)) >> 16;
    return (short)r;
}
__device__ __forceinline__ float bf2f(short s) {
    return __uint_as_float(((unsigned)(unsigned short)s) << 16);
}
// LDS XOR swizzle: rows with stride % 128B == 0 spread across banks (bits 4-6)
#define SWZ(row, byte) ((byte) ^ (((row) & 7) << 4))

__global__ __launch_bounds__(256) void convert_w(
    const float* __restrict__ src, short* __restrict__ dst, int n)
{
    for (int i = blockIdx.x * 256 + threadIdx.x; i < n; i += gridDim.x * 256)
        dst[i] = f2bf(src[i]);
}

// Y_bf16[row, d] = bf16( sum_k X[row,k]*W[d,k] + bias[d] );  K = DT_ = 256.
// BM=64 rows/block, 512 threads = 8 waves (wm 0..3 rows, wn 0..1 col-halves).
__global__ __launch_bounds__(512, 4) void proj_mfma(
    const float* __restrict__ X, const short* __restrict__ Wb,
    const float* __restrict__ bias, short* __restrict__ Y)
{
    __shared__ short A_lds[64 * DT_];   // 32 KB swizzled bf16
    const int t = threadIdx.x;
    const int lane = t & 63, w = t >> 6;
    const int wm = w >> 1, wn = w & 1;
    const int r16 = lane & 15, g = lane >> 4;
    const long row0 = (long)blockIdx.x * 64;

    const float4* X4 = (const float4*)(X + row0 * DT_);
    for (int i = t; i < 64 * (DT_ / 4); i += 512) {
        float4 v = X4[i];
        int row = i / (DT_ / 4);
        int k4  = i % (DT_ / 4);
        short4 s;
        s.x = f2bf(v.x); s.y = f2bf(v.y); s.z = f2bf(v.z); s.w = f2bf(v.w);
        *(short4*)((char*)A_lds + SWZ(row, row * (DT_ * 2) + k4 * 8)) = s;
    }
    __syncthreads();

    const int arow = wm * 16 + r16;
    for (int ct = 0; ct < 5; ++ct) {
        const int cb = wn * 320 + ct * 64;
        f32x4 acc0 = {0.f,0.f,0.f,0.f}, acc1 = acc0, acc2 = acc0, acc3 = acc0;
        const short* Wbase = Wb + (long)(cb + r16) * DT_ + g * 8;
        #pragma unroll
        for (int kc = 0; kc < DT_ / 32; ++kc) {
            bf16x8 a = *(const bf16x8*)((const char*)A_lds +
                        SWZ(arow, arow * (DT_ * 2) + kc * 64 + g * 16));
            bf16x8 b0 = *(const bf16x8*)(Wbase + 0 * 16 * DT_ + kc * 32);
            bf16x8 b1 = *(const bf16x8*)(Wbase + 1 * 16 * DT_ + kc * 32);
            acc0 = __builtin_amdgcn_mfma_f32_16x16x32_bf16(a, b0, acc0, 0, 0, 0);
            acc1 = __builtin_amdgcn_mfma_f32_16x16x32_bf16(a, b1, acc1, 0, 0, 0);
            bf16x8 b2 = *(const bf16x8*)(Wbase + 2 * 16 * DT_ + kc * 32);
            bf16x8 b3 = *(const bf16x8*)(Wbase + 3 * 16 * DT_ + kc * 32);
            acc2 = __builtin_amdgcn_mfma_f32_16x16x32_bf16(a, b2, acc2, 0, 0, 0);
            acc3 = __builtin_amdgcn_mfma_f32_16x16x32_bf16(a, b3, acc3, 0, 0, 0);
        }
        // C/D: col = lane&15, row = (lane>>4)*4 + i
        #pragma unroll
        for (int f = 0; f < 4; ++f) {
            const f32x4 acc = (f == 0) ? acc0 : (f == 1) ? acc1 : (f == 2) ? acc2 : acc3;
            const int col = cb + f * 16 + r16;
            const float bv = bias[col];
            #pragma unroll
            for (int i = 0; i < 4; ++i)
                Y[(row0 + wm * 16 + g * 4 + i) * (long)D_ + col] = f2bf(acc[i] + bv);
        }
    }
}

// Fused attention + aggregation for one batch b per block (256 threads, 4 waves).
// scores GEMM (MFMA) -> in-register softmax over m -> sum over h with qw[n]
// weights -> agg[m] -> softmax -> aw / out_tail.
__global__ __launch_bounds__(256) void attn2(
    const short* __restrict__ Qb, const short* __restrict__ Kb,
    float* __restrict__ aw, float* __restrict__ out_tail)
{
    __shared__ float qn_l[N_];
    __shared__ float qw_l[N_];
    __shared__ float aggp[4][MT_ * 16];
    __shared__ float red2[2];
    const int t = threadIdx.x;
    const int lane = t & 63, wm = t >> 6;     // wm 0..3: n-rows wm*16..+15
    const int r16 = lane & 15, g = lane >> 4;
    const int b = blockIdx.x;

    // --- query-norm softmax weights qw[n] (from bf16 Qb, fp32 accum) ---
    {
        const short* qrow = Qb + ((long)(b * N_ + wm * 16 + r16)) * D_ + g * 160;
        float ss = 0.f;
        #pragma unroll
        for (int j = 0; j < 20; ++j) {
            bf16x8 v = *(const bf16x8*)(qrow + j * 8);
            #pragma unroll
            for (int e = 0; e < 8; ++e) { float f = bf2f(v[e]); ss += f * f; }
        }
        ss += __shfl_xor(ss, 16);
        ss += __shfl_xor(ss, 32);        // reduce over g (4 k-quarters)
        if (g == 0) qn_l[wm * 16 + r16] = ss;
    }
    __syncthreads();
    if (wm == 0) {
        float v = sqrtf(qn_l[lane]);
        float mx = wave_reduce_max(v);
        float e = __expf(v - mx);
        float s = wave_reduce_sum(e);
        qw_l[lane] = e / s;
    }
    __syncthreads();

    float qwr[4];
    #pragma unroll
    for (int i = 0; i < 4; ++i) qwr[i] = qw_l[wm * 16 + g * 4 + i];

    const float inv_scale = 0.0395284707521047f;   // 1/sqrt(640)
    float aggl[MT_];
    #pragma unroll
    for (int mt = 0; mt < MT_; ++mt) aggl[mt] = 0.f;

    for (int h = 0; h < NH_; ++h) {
        const short* qbase = Qb + ((long)(b * N_ + wm * 16 + r16)) * D_ + h * HD_ + g * 8;
        bf16x8 a0 = *(const bf16x8*)(qbase);
        bf16x8 a1 = *(const bf16x8*)(qbase + 32);
        f32x4 acc[MT_];
        #pragma unroll
        for (int mt = 0; mt < MT_; ++mt) {
            f32x4 z = {0.f,0.f,0.f,0.f};
            const short* kbase = Kb + ((long)(b * H_ + mt * 16 + r16)) * D_ + h * HD_ + g * 8;
            bf16x8 b0 = *(const bf16x8*)(kbase);
            bf16x8 b1 = *(const bf16x8*)(kbase + 32);
            z = __builtin_amdgcn_mfma_f32_16x16x32_bf16(a0, b0, z, 0, 0, 0);
            z = __builtin_amdgcn_mfma_f32_16x16x32_bf16(a1, b1, z, 0, 0, 0);
            acc[mt] = z;
        }
        // softmax over m for rows n = wm*16 + g*4 + i (lane holds col m = mt*16+r16)
        const bool tailok = (r16 < 8);   // mt==12 valid only for m<200
        float mx[4] = {-INFINITY, -INFINITY, -INFINITY, -INFINITY};
        #pragma unroll
        for (int mt = 0; mt < MT_; ++mt) {
            const bool valid = (mt < 12) || tailok;
            #pragma unroll
            for (int i = 0; i < 4; ++i)
                if (valid) mx[i] = fmaxf(mx[i], acc[mt][i]);
        }
        #pragma unroll
        for (int i = 0; i < 4; ++i) mx[i] = red16_max(mx[i]);
        float sum[4] = {0.f, 0.f, 0.f, 0.f};
        #pragma unroll
        for (int mt = 0; mt < MT_; ++mt) {
            const bool valid = (mt < 12) || tailok;
            #pragma unroll
            for (int i = 0; i < 4; ++i) {
                float e = valid ? __expf((acc[mt][i] - mx[i]) * inv_scale) : 0.f;
                acc[mt][i] = e;
                sum[i] += e;
            }
        }
        float fct[4];
        #pragma unroll
        for (int i = 0; i < 4; ++i) fct[i] = qwr[i] / red16_sum(sum[i]);
        #pragma unroll
        for (int mt = 0; mt < MT_; ++mt)
            aggl[mt] += acc[mt][0] * fct[0] + acc[mt][1] * fct[1]
                      + acc[mt][2] * fct[2] + acc[mt][3] * fct[3];
    }
    // reduce over g (row groups) -> wave partial agg for m = mt*16 + r16
    #pragma unroll
    for (int mt = 0; mt < MT_; ++mt) {
        aggl[mt] += __shfl_xor(aggl[mt], 16);
        aggl[mt] += __shfl_xor(aggl[mt], 32);
    }
    if (g == 0) {
        #pragma unroll
        for (int mt = 0; mt < MT_; ++mt) aggp[wm][mt * 16 + r16] = aggl[mt];
    }
    __syncthreads();
    if (t < MT_ * 16) {
        float v = aggp[0][t] + aggp[1][t] + aggp[2][t] + aggp[3][t];
        aggp[0][t] = v;
    }
    __syncthreads();
    if (wm == 0) {
        float v0 = aggp[0][lane], v1 = aggp[0][lane + 64], v2 = aggp[0][lane + 128];
        const bool has3 = lane < (H_ - 192);
        float v3 = has3 ? aggp[0][lane + 192] : -INFINITY;
        float mx = wave_reduce_max(fmaxf(fmaxf(v0, v1), fmaxf(v2, v3)));
        float s = __expf(v0 - mx) + __expf(v1 - mx) + __expf(v2 - mx)
                + (has3 ? __expf(v3 - mx) : 0.f);
        s = wave_reduce_sum(s);
        if (lane == 0) { red2[0] = mx; red2[1] = s; }
    }
    __syncthreads();
    if (t < H_) {
        float v = __expf(aggp[0][t] - red2[0]) / red2[1];
        aw[b * H_ + t] = v;
        out_tail[b * H_ + t] = v;
    }
}

// gate GEMM + blend + LayerNorm. BM=64 rows/block, 512 threads, K = 640.
// Accumulators held in registers for ALL 5 col-tiles; z written into A_lds
// after the GEMM (A dead by then) -> LDS 80 KB, 2 blocks/CU.
__global__ __launch_bounds__(512, 4) void out_mfma(
    const float* __restrict__ clicked, const float* __restrict__ aw,
    const short* __restrict__ Wgb, const float* __restrict__ bg,
    const float* __restrict__ gamma, const float* __restrict__ beta,
    float* __restrict__ out)
{
    __shared__ short A_lds[64 * D_];   // 80 KB
    const int t = threadIdx.x;
    const int lane = t & 63, w = t >> 6;
    const int wm = w >> 1, wn = w & 1;
    const int r16 = lane & 15, g = lane >> 4;
    const long row0 = (long)blockIdx.x * 64;

    // stage weighted = aw[row] * clicked[row,:] -> swizzled bf16 LDS
    {
        const float4* C4 = (const float4*)(clicked + row0 * D_);
        for (int i = t; i < 64 * (D_ / 4); i += 512) {
            int row = i / (D_ / 4);
            int k4  = i % (D_ / 4);
            float a = aw[row0 + row];
            float4 v = C4[i];
            short4 s;
            s.x = f2bf(v.x * a); s.y = f2bf(v.y * a);
            s.z = f2bf(v.z * a); s.w = f2bf(v.w * a);
            *(short4*)((char*)A_lds + SWZ(row, row * (D_ * 2) + k4 * 8)) = s;
        }
    }
    __syncthreads();

    const int arow = wm * 16 + r16;
    f32x4 acc[5][4];
    #pragma unroll
    for (int ct = 0; ct < 5; ++ct)
        #pragma unroll
        for (int f = 0; f < 4; ++f) acc[ct][f] = (f32x4){0.f,0.f,0.f,0.f};

    #pragma unroll
    for (int ct = 0; ct < 5; ++ct) {
        const int cb = wn * 320 + ct * 64;
        const short* Wbase = Wgb + (long)(cb + r16) * D_ + g * 8;
        for (int kc = 0; kc < D_ / 32; ++kc) {
            bf16x8 a = *(const bf16x8*)((const char*)A_lds +
                        SWZ(arow, arow * (D_ * 2) + kc * 64 + g * 16));
            bf16x8 b0 = *(const bf16x8*)(Wbase + 0 * 16 * D_ + kc * 32);
            bf16x8 b1 = *(const bf16x8*)(Wbase + 1 * 16 * D_ + kc * 32);
            acc[ct][0] = __builtin_amdgcn_mfma_f32_16x16x32_bf16(a, b0, acc[ct][0], 0, 0, 0);
            acc[ct][1] = __builtin_amdgcn_mfma_f32_16x16x32_bf16(a, b1, acc[ct][1], 0, 0, 0);
            bf16x8 b2 = *(const bf16x8*)(Wbase + 2 * 16 * D_ + kc * 32);
            bf16x8 b3 = *(const bf16x8*)(Wbase + 3 * 16 * D_ + kc * 32);
            acc[ct][2] = __builtin_amdgcn_mfma_f32_16x16x32_bf16(a, b2, acc[ct][2], 0, 0, 0);
            acc[ct][3] = __builtin_amdgcn_mfma_f32_16x16x32_bf16(a, b3, acc[ct][3], 0, 0, 0);
        }
    }
    __syncthreads();   // everyone done READING A_lds

    // write z (bf16, plain [row][col]) into A_lds
    #pragma unroll
    for (int ct = 0; ct < 5; ++ct) {
        #pragma unroll
        for (int f = 0; f < 4; ++f) {
            const int col = wn * 320 + ct * 64 + f * 16 + r16;
            const float bv = bg[col];
            #pragma unroll
            for (int i = 0; i < 4; ++i)
                A_lds[(wm * 16 + g * 4 + i) * D_ + col] = f2bf(acc[ct][f][i] + bv);
        }
    }
    __syncthreads();

    // blend + LayerNorm: wave w handles rows w*8 .. w*8+7
    for (int rr = 0; rr < 8; ++rr) {
        const int r = w * 8 + rr;
        const long base = (row0 + r) * (long)D_;
        const float aww = aw[row0 + r];
        float ov[10];
        float s = 0.f, sq = 0.f;
        #pragma unroll
        for (int i = 0; i < 10; ++i) {
            const int c = lane + 64 * i;
            float cl = clicked[base + c];
            float z  = bf2f(A_lds[r * D_ + c]);
            float gt = 1.f / (1.f + __expf(-z));
            float o  = gt * (aww * cl) + (1.f - gt) * cl;
            ov[i] = o; s += o; sq += o * o;
        }
        s  = wave_reduce_sum(s);
        sq = wave_reduce_sum(sq);
        const float mu  = s * (1.f / D_);
        const float var = sq * (1.f / D_) - mu * mu;
        const float rinv = 1.0f / sqrtf(var + 1e-5f);
        #pragma unroll
        for (int i = 0; i < 10; ++i) {
            const int c = lane + 64 * i;
            out[base + c] = (ov[i] - mu) * rinv * gamma[c] + beta[c];
        }
    }
}

extern "C" void kernel_launch(void* const* d_in, const int* in_sizes, int n_in,
                              void* d_out, int out_size, void* d_ws, size_t ws_size,
                              hipStream_t stream) {
    const float* clicked_news   = (const float*)d_in[0];   // [B,H,D]
    const float* clicked_topics = (const float*)d_in[1];   // [B,H,Dt]
    const float* cand_topics    = (const float*)d_in[2];   // [B,N,Dt]
    const float* Wq = (const float*)d_in[3];
    const float* bq = (const float*)d_in[4];
    const float* Wk = (const float*)d_in[5];
    const float* bk = (const float*)d_in[6];
    // d_in[7], d_in[8] = Wv, bv: dead code w.r.t. outputs
    const float* Wg = (const float*)d_in[9];
    const float* bg = (const float*)d_in[10];
    const float* ln_gamma = (const float*)d_in[11];
    const float* ln_beta  = (const float*)d_in[12];

    float* out = (float*)d_out;
    float* ws  = (float*)d_ws;

    // ws layout: aw (f32), then bf16 arrays
    float* aw = ws;                                     // B*H floats
    short* sbase = (short*)(ws + (long)B_ * H_);
    short* Qb   = sbase;                                // B*N*D  = 10,485,760
    short* Wq_b = Qb + (long)B_ * N_ * D_;              // 163,840
    short* Wg_b = Wq_b + (long)D_ * DT_;                // 409,600
    short* Wk_b = Wg_b + (long)D_ * D_;                 // 163,840
    // Kb (bf16) lives at the start of d_out: read by attn2, then overwritten
    // by out_mfma's final output. Padded by 8 rows for the mt=12 tail reads.
    short* Kb = (short*)d_out;                          // (B*H + 8) * D_ shorts
    float* out_tail = out + (long)B_ * H_ * D_;         // attn_weights_agg

    convert_w<<<128, 256, 0, stream>>>(Wq, Wq_b, D_ * DT_);
    convert_w<<<128, 256, 0, stream>>>(Wk, Wk_b, D_ * DT_);
    convert_w<<<256, 256, 0, stream>>>(Wg, Wg_b, D_ * D_);

    proj_mfma<<<(B_ * N_) / 64, 512, 0, stream>>>(cand_topics, Wq_b, bq, Qb);
    proj_mfma<<<(B_ * H_) / 64, 512, 0, stream>>>(clicked_topics, Wk_b, bk, Kb);
    attn2<<<B_, 256, 0, stream>>>(Qb, Kb, aw, out_tail);
    out_mfma<<<(B_ * H_) / 64, 512, 0, stream>>>(clicked_news, aw, Wg_b, bg,
                                                 ln_gamma, ln_beta, out);
}

// Round 5
// 314.466 us; speedup vs baseline: 14.2779x; 2.2688x over previous
//
#include <hip/hip_runtime.h>
#include <math.h>

#define B_  256
#define H_  200
#define N_  64
#define D_  640
#define DT_ 256
#define NH_ 10
#define HD_ 64
#define MT_ 13   // 13 m-tiles of 16 cover 208 >= 200

typedef __attribute__((ext_vector_type(8))) short bf16x8;
typedef __attribute__((ext_vector_type(4))) float f32x4;

__device__ __forceinline__ float wave_reduce_sum(float v) {
    #pragma unroll
    for (int m = 32; m > 0; m >>= 1) v += __shfl_xor(v, m);
    return v;
}
__device__ __forceinline__ float wave_reduce_max(float v) {
    #pragma unroll
    for (int m = 32; m > 0; m >>= 1) v = fmaxf(v, __shfl_xor(v, m));
    return v;
}
__device__ __forceinline__ float red16_sum(float v) {   // reduce over lane&15 group
    #pragma unroll
    for (int m = 1; m < 16; m <<= 1) v += __shfl_xor(v, m);
    return v;
}
__device__ __forceinline__ float red16_max(float v) {
    #pragma unroll
    for (int m = 1; m < 16; m <<= 1) v = fmaxf(v, __shfl_xor(v, m));
    return v;
}
__device__ __forceinline__ short f2bf(float x) {   // RNE bf16
    unsigned u = __float_as_uint(x);
    unsigned r = (u + 0x7fffu + ((u >> 16) & 1u)) >> 16;
    return (short)r;
}
__device__ __forceinline__ float bf2f(short s) {
    return __uint_as_float(((unsigned)(unsigned short)s) << 16);
}
// LDS XOR swizzle: rows with stride % 128B == 0 spread across banks (bits 4-6)
#define SWZ(row, byte) ((byte) ^ (((row) & 7) << 4))

__global__ __launch_bounds__(256) void convert_w(
    const float* __restrict__ src, short* __restrict__ dst, int n)
{
    for (int i = blockIdx.x * 256 + threadIdx.x; i < n; i += gridDim.x * 256)
        dst[i] = f2bf(src[i]);
}

// Y_bf16[row, d] = bf16( sum_k X[row,k]*W[d,k] + bias[d] );  K = DT_ = 256.
// BM=64 rows/block, 512 threads = 8 waves. Wave w owns cols [w*80, w*80+80)
// (5 col-tiles of 16) and ALL 4 row-tiles -> 20 MFMA per 5 B-loads.
__global__ __launch_bounds__(512, 2) void proj_mfma(
    const float* __restrict__ X, const short* __restrict__ Wb,
    const float* __restrict__ bias, short* __restrict__ Y)
{
    __shared__ short A_lds[64 * DT_];   // 32 KB swizzled bf16
    const int t = threadIdx.x;
    const int lane = t & 63, w = t >> 6;
    const int r16 = lane & 15, g = lane >> 4;
    const long row0 = (long)blockIdx.x * 64;

    const float4* X4 = (const float4*)(X + row0 * DT_);
    for (int i = t; i < 64 * (DT_ / 4); i += 512) {
        float4 v = X4[i];
        int row = i / (DT_ / 4);
        int k4  = i % (DT_ / 4);
        short4 s;
        s.x = f2bf(v.x); s.y = f2bf(v.y); s.z = f2bf(v.z); s.w = f2bf(v.w);
        *(short4*)((char*)A_lds + SWZ(row, row * (DT_ * 2) + k4 * 8)) = s;
    }
    __syncthreads();

    f32x4 acc[5][4];
    #pragma unroll
    for (int ct = 0; ct < 5; ++ct)
        #pragma unroll
        for (int rt = 0; rt < 4; ++rt) acc[ct][rt] = (f32x4){0.f,0.f,0.f,0.f};

    const short* Wbase = Wb + (long)(w * 80 + r16) * DT_ + g * 8;
    #pragma unroll 2
    for (int kc = 0; kc < DT_ / 32; ++kc) {
        bf16x8 a[4];
        #pragma unroll
        for (int rt = 0; rt < 4; ++rt) {
            const int row = rt * 16 + r16;
            a[rt] = *(const bf16x8*)((const char*)A_lds +
                     SWZ(row, row * (DT_ * 2) + kc * 64 + g * 16));
        }
        bf16x8 bb[5];
        #pragma unroll
        for (int ct = 0; ct < 5; ++ct)
            bb[ct] = *(const bf16x8*)(Wbase + ct * 16 * DT_ + kc * 32);
        #pragma unroll
        for (int ct = 0; ct < 5; ++ct)
            #pragma unroll
            for (int rt = 0; rt < 4; ++rt)
                acc[ct][rt] = __builtin_amdgcn_mfma_f32_16x16x32_bf16(
                                  a[rt], bb[ct], acc[ct][rt], 0, 0, 0);
    }
    // C/D: out-col = lane&15 (within col-tile), out-row = (lane>>4)*4 + i
    #pragma unroll
    for (int ct = 0; ct < 5; ++ct) {
        const int col = w * 80 + ct * 16 + r16;
        const float bv = bias[col];
        #pragma unroll
        for (int rt = 0; rt < 4; ++rt)
            #pragma unroll
            for (int i = 0; i < 4; ++i)
                Y[(row0 + rt * 16 + g * 4 + i) * (long)D_ + col] =
                    f2bf(acc[ct][rt][i] + bv);
    }
}

// Fused attention + aggregation for one batch b per block (256 threads, 4 waves).
__global__ __launch_bounds__(256) void attn2(
    const short* __restrict__ Qb, const short* __restrict__ Kb,
    float* __restrict__ aw, float* __restrict__ out_tail)
{
    __shared__ float qn_l[N_];
    __shared__ float qw_l[N_];
    __shared__ float aggp[4][MT_ * 16];
    __shared__ float red2[2];
    const int t = threadIdx.x;
    const int lane = t & 63, wm = t >> 6;     // wm 0..3: n-rows wm*16..+15
    const int r16 = lane & 15, g = lane >> 4;
    const int b = blockIdx.x;

    // --- query-norm softmax weights qw[n] (from bf16 Qb, fp32 accum) ---
    {
        const short* qrow = Qb + ((long)(b * N_ + wm * 16 + r16)) * D_ + g * 160;
        float ss = 0.f;
        #pragma unroll
        for (int j = 0; j < 20; ++j) {
            bf16x8 v = *(const bf16x8*)(qrow + j * 8);
            #pragma unroll
            for (int e = 0; e < 8; ++e) { float f = bf2f(v[e]); ss += f * f; }
        }
        ss += __shfl_xor(ss, 16);
        ss += __shfl_xor(ss, 32);        // reduce over g (4 k-quarters)
        if (g == 0) qn_l[wm * 16 + r16] = ss;
    }
    __syncthreads();
    if (wm == 0) {
        float v = sqrtf(qn_l[lane]);
        float mx = wave_reduce_max(v);
        float e = __expf(v - mx);
        float s = wave_reduce_sum(e);
        qw_l[lane] = e / s;
    }
    __syncthreads();

    float qwr[4];
    #pragma unroll
    for (int i = 0; i < 4; ++i) qwr[i] = qw_l[wm * 16 + g * 4 + i];

    const float inv_scale = 0.0395284707521047f;   // 1/sqrt(640)
    float aggl[MT_];
    #pragma unroll
    for (int mt = 0; mt < MT_; ++mt) aggl[mt] = 0.f;

    for (int h = 0; h < NH_; ++h) {
        const short* qbase = Qb + ((long)(b * N_ + wm * 16 + r16)) * D_ + h * HD_ + g * 8;
        bf16x8 a0 = *(const bf16x8*)(qbase);
        bf16x8 a1 = *(const bf16x8*)(qbase + 32);
        f32x4 acc[MT_];
        #pragma unroll
        for (int mt = 0; mt < MT_; ++mt) {
            f32x4 z = {0.f,0.f,0.f,0.f};
            const short* kbase = Kb + ((long)(b * H_ + mt * 16 + r16)) * D_ + h * HD_ + g * 8;
            bf16x8 b0 = *(const bf16x8*)(kbase);
            bf16x8 b1 = *(const bf16x8*)(kbase + 32);
            z = __builtin_amdgcn_mfma_f32_16x16x32_bf16(a0, b0, z, 0, 0, 0);
            z = __builtin_amdgcn_mfma_f32_16x16x32_bf16(a1, b1, z, 0, 0, 0);
            acc[mt] = z;
        }
        // softmax over m for rows n = wm*16 + g*4 + i (lane holds col m = mt*16+r16)
        const bool tailok = (r16 < 8);   // mt==12 valid only for m<200
        float mx[4] = {-INFINITY, -INFINITY, -INFINITY, -INFINITY};
        #pragma unroll
        for (int mt = 0; mt < MT_; ++mt) {
            const bool valid = (mt < 12) || tailok;
            #pragma unroll
            for (int i = 0; i < 4; ++i)
                if (valid) mx[i] = fmaxf(mx[i], acc[mt][i]);
        }
        #pragma unroll
        for (int i = 0; i < 4; ++i) mx[i] = red16_max(mx[i]);
        float sum[4] = {0.f, 0.f, 0.f, 0.f};
        #pragma unroll
        for (int mt = 0; mt < MT_; ++mt) {
            const bool valid = (mt < 12) || tailok;
            #pragma unroll
            for (int i = 0; i < 4; ++i) {
                float e = valid ? __expf((acc[mt][i] - mx[i]) * inv_scale) : 0.f;
                acc[mt][i] = e;
                sum[i] += e;
            }
        }
        float fct[4];
        #pragma unroll
        for (int i = 0; i < 4; ++i) fct[i] = qwr[i] / red16_sum(sum[i]);
        #pragma unroll
        for (int mt = 0; mt < MT_; ++mt)
            aggl[mt] += acc[mt][0] * fct[0] + acc[mt][1] * fct[1]
                      + acc[mt][2] * fct[2] + acc[mt][3] * fct[3];
    }
    // reduce over g (row groups) -> wave partial agg for m = mt*16 + r16
    #pragma unroll
    for (int mt = 0; mt < MT_; ++mt) {
        aggl[mt] += __shfl_xor(aggl[mt], 16);
        aggl[mt] += __shfl_xor(aggl[mt], 32);
    }
    if (g == 0) {
        #pragma unroll
        for (int mt = 0; mt < MT_; ++mt) aggp[wm][mt * 16 + r16] = aggl[mt];
    }
    __syncthreads();
    if (t < MT_ * 16) {
        float v = aggp[0][t] + aggp[1][t] + aggp[2][t] + aggp[3][t];
        aggp[0][t] = v;
    }
    __syncthreads();
    if (wm == 0) {
        float v0 = aggp[0][lane], v1 = aggp[0][lane + 64], v2 = aggp[0][lane + 128];
        const bool has3 = lane < (H_ - 192);
        float v3 = has3 ? aggp[0][lane + 192] : -INFINITY;
        float mx = wave_reduce_max(fmaxf(fmaxf(v0, v1), fmaxf(v2, v3)));
        float s = __expf(v0 - mx) + __expf(v1 - mx) + __expf(v2 - mx)
                + (has3 ? __expf(v3 - mx) : 0.f);
        s = wave_reduce_sum(s);
        if (lane == 0) { red2[0] = mx; red2[1] = s; }
    }
    __syncthreads();
    if (t < H_) {
        float v = __expf(aggp[0][t] - red2[0]) / red2[1];
        aw[b * H_ + t] = v;
        out_tail[b * H_ + t] = v;
    }
}

// gate GEMM + blend + LayerNorm. BM=64 rows/block, 512 threads, K = 640.
// Wave w owns cols [w*80, w*80+80), all 4 row-tiles: acc[5][4] in regs.
// z written into A_lds after the GEMM (A dead then) -> LDS 80 KB.
__global__ __launch_bounds__(512, 2) void out_mfma(
    const float* __restrict__ clicked, const float* __restrict__ aw,
    const short* __restrict__ Wgb, const float* __restrict__ bg,
    const float* __restrict__ gamma, const float* __restrict__ beta,
    float* __restrict__ out)
{
    __shared__ short A_lds[64 * D_];   // 80 KB
    const int t = threadIdx.x;
    const int lane = t & 63, w = t >> 6;
    const int r16 = lane & 15, g = lane >> 4;
    const long row0 = (long)blockIdx.x * 64;

    // stage weighted = aw[row] * clicked[row,:] -> swizzled bf16 LDS
    {
        const float4* C4 = (const float4*)(clicked + row0 * D_);
        for (int i = t; i < 64 * (D_ / 4); i += 512) {
            int row = i / (D_ / 4);
            int k4  = i % (D_ / 4);
            float a = aw[row0 + row];
            float4 v = C4[i];
            short4 s;
            s.x = f2bf(v.x * a); s.y = f2bf(v.y * a);
            s.z = f2bf(v.z * a); s.w = f2bf(v.w * a);
            *(short4*)((char*)A_lds + SWZ(row, row * (D_ * 2) + k4 * 8)) = s;
        }
    }
    __syncthreads();

    f32x4 acc[5][4];
    #pragma unroll
    for (int ct = 0; ct < 5; ++ct)
        #pragma unroll
        for (int rt = 0; rt < 4; ++rt) acc[ct][rt] = (f32x4){0.f,0.f,0.f,0.f};

    const short* Wbase = Wgb + (long)(w * 80 + r16) * D_ + g * 8;
    #pragma unroll 2
    for (int kc = 0; kc < D_ / 32; ++kc) {
        bf16x8 a[4];
        #pragma unroll
        for (int rt = 0; rt < 4; ++rt) {
            const int row = rt * 16 + r16;
            a[rt] = *(const bf16x8*)((const char*)A_lds +
                     SWZ(row, row * (D_ * 2) + kc * 64 + g * 16));
        }
        bf16x8 bb[5];
        #pragma unroll
        for (int ct = 0; ct < 5; ++ct)
            bb[ct] = *(const bf16x8*)(Wbase + ct * 16 * D_ + kc * 32);
        #pragma unroll
        for (int ct = 0; ct < 5; ++ct)
            #pragma unroll
            for (int rt = 0; rt < 4; ++rt)
                acc[ct][rt] = __builtin_amdgcn_mfma_f32_16x16x32_bf16(
                                  a[rt], bb[ct], acc[ct][rt], 0, 0, 0);
    }
    __syncthreads();   // everyone done READING A_lds

    // write z (bf16, plain [row][col]) into A_lds
    #pragma unroll
    for (int ct = 0; ct < 5; ++ct) {
        const int col = w * 80 + ct * 16 + r16;
        const float bv = bg[col];
        #pragma unroll
        for (int rt = 0; rt < 4; ++rt)
            #pragma unroll
            for (int i = 0; i < 4; ++i)
                A_lds[(rt * 16 + g * 4 + i) * D_ + col] = f2bf(acc[ct][rt][i] + bv);
    }
    __syncthreads();

    // blend + LayerNorm: wave w handles rows w*8 .. w*8+7
    for (int rr = 0; rr < 8; ++rr) {
        const int r = w * 8 + rr;
        const long base = (row0 + r) * (long)D_;
        const float aww = aw[row0 + r];
        float ov[10];
        float s = 0.f, sq = 0.f;
        #pragma unroll
        for (int i = 0; i < 10; ++i) {
            const int c = lane + 64 * i;
            float cl = clicked[base + c];
            float z  = bf2f(A_lds[r * D_ + c]);
            float gt = 1.f / (1.f + __expf(-z));
            float o  = gt * (aww * cl) + (1.f - gt) * cl;
            ov[i] = o; s += o; sq += o * o;
        }
        s  = wave_reduce_sum(s);
        sq = wave_reduce_sum(sq);
        const float mu  = s * (1.f / D_);
        const float var = sq * (1.f / D_) - mu * mu;
        const float rinv = 1.0f / sqrtf(var + 1e-5f);
        #pragma unroll
        for (int i = 0; i < 10; ++i) {
            const int c = lane + 64 * i;
            out[base + c] = (ov[i] - mu) * rinv * gamma[c] + beta[c];
        }
    }
}

extern "C" void kernel_launch(void* const* d_in, const int* in_sizes, int n_in,
                              void* d_out, int out_size, void* d_ws, size_t ws_size,
                              hipStream_t stream) {
    const float* clicked_news   = (const float*)d_in[0];   // [B,H,D]
    const float* clicked_topics = (const float*)d_in[1];   // [B,H,Dt]
    const float* cand_topics    = (const float*)d_in[2];   // [B,N,Dt]
    const float* Wq = (const float*)d_in[3];
    const float* bq = (const float*)d_in[4];
    const float* Wk = (const float*)d_in[5];
    const float* bk = (const float*)d_in[6];
    // d_in[7], d_in[8] = Wv, bv: dead code w.r.t. outputs
    const float* Wg = (const float*)d_in[9];
    const float* bg = (const float*)d_in[10];
    const float* ln_gamma = (const float*)d_in[11];
    const float* ln_beta  = (const float*)d_in[12];

    float* out = (float*)d_out;
    float* ws  = (float*)d_ws;

    // ws layout: aw (f32), then bf16 arrays
    float* aw = ws;                                     // B*H floats
    short* sbase = (short*)(ws + (long)B_ * H_);
    short* Qb   = sbase;                                // B*N*D  = 10,485,760
    short* Wq_b = Qb + (long)B_ * N_ * D_;              // 163,840
    short* Wg_b = Wq_b + (long)D_ * DT_;                // 409,600
    short* Wk_b = Wg_b + (long)D_ * D_;                 // 163,840
    // Kb (bf16) lives at the start of d_out: read by attn2, then overwritten
    // by out_mfma's final output. Padded by 8 rows for the mt=12 tail reads.
    short* Kb = (short*)d_out;                          // (B*H + 8) * D_ shorts
    float* out_tail = out + (long)B_ * H_ * D_;         // attn_weights_agg

    convert_w<<<128, 256, 0, stream>>>(Wq, Wq_b, D_ * DT_);
    convert_w<<<128, 256, 0, stream>>>(Wk, Wk_b, D_ * DT_);
    convert_w<<<256, 256, 0, stream>>>(Wg, Wg_b, D_ * D_);

    proj_mfma<<<(B_ * N_) / 64, 512, 0, stream>>>(cand_topics, Wq_b, bq, Qb);
    proj_mfma<<<(B_ * H_) / 64, 512, 0, stream>>>(clicked_topics, Wk_b, bk, Kb);
    attn2<<<B_, 256, 0, stream>>>(Qb, Kb, aw, out_tail);
    out_mfma<<<(B_ * H_) / 64, 512, 0, stream>>>(clicked_news, aw, Wg_b, bg,
                                                 ln_gamma, ln_beta, out);
}

// Round 6
// 311.608 us; speedup vs baseline: 14.4088x; 1.0092x over previous
//
#include <hip/hip_runtime.h>
#include <math.h>

#define B_  256
#define H_  200
#define N_  64
#define D_  640
#define DT_ 256
#define NH_ 10
#define HD_ 64
#define MT_ 13   // 13 m-tiles of 16 cover 208 >= 200

typedef __attribute__((ext_vector_type(8))) short bf16x8;
typedef __attribute__((ext_vector_type(4))) float f32x4;

__device__ __forceinline__ float wave_reduce_sum(float v) {
    #pragma unroll
    for (int m = 32; m > 0; m >>= 1) v += __shfl_xor(v, m);
    return v;
}
__device__ __forceinline__ float wave_reduce_max(float v) {
    #pragma unroll
    for (int m = 32; m > 0; m >>= 1) v = fmaxf(v, __shfl_xor(v, m));
    return v;
}
__device__ __forceinline__ float red16_sum(float v) {   // reduce over lane&15 group
    #pragma unroll
    for (int m = 1; m < 16; m <<= 1) v += __shfl_xor(v, m);
    return v;
}
__device__ __forceinline__ float red16_max(float v) {
    #pragma unroll
    for (int m = 1; m < 16; m <<= 1) v = fmaxf(v, __shfl_xor(v, m));
    return v;
}
__device__ __forceinline__ short f2bf(float x) {   // RNE bf16
    unsigned u = __float_as_uint(x);
    unsigned r = (u + 0x7fffu + ((u >> 16) & 1u)) >> 16;
    return (short)r;
}
__device__ __forceinline__ float bf2f(short s) {
    return __uint_as_float(((unsigned)(unsigned short)s) << 16);
}
// LDS XOR swizzle: rows with stride % 128B == 0 spread across banks (bits 4-6)
#define SWZ(row, byte) ((byte) ^ (((row) & 7) << 4))

__global__ __launch_bounds__(256) void convert_w(
    const float* __restrict__ src, short* __restrict__ dst, int n)
{
    for (int i = blockIdx.x * 256 + threadIdx.x; i < n; i += gridDim.x * 256)
        dst[i] = f2bf(src[i]);
}

// Y_bf16[row, d] = bf16( sum_k X[row,k]*W[d,k] + bias[d] );  K = DT_ = 256.
// BM=64 rows/block, 512 threads = 8 waves. Wave w owns cols [w*80, w*80+80),
// all 4 row-tiles. 2-stage register pipeline over kc (explicit prefetch).
__global__ __launch_bounds__(512, 2) void proj_mfma(
    const float* __restrict__ X, const short* __restrict__ Wb,
    const float* __restrict__ bias, short* __restrict__ Y)
{
    __shared__ short A_lds[64 * DT_];   // 32 KB swizzled bf16
    const int t = threadIdx.x;
    const int lane = t & 63, w = t >> 6;
    const int r16 = lane & 15, g = lane >> 4;
    const long row0 = (long)blockIdx.x * 64;

    // stage X -> bf16 LDS: one row per 8 threads, loads batched in regs
    {
        const int srow = t >> 3, sc = t & 7;
        const float4* src = (const float4*)(X + (row0 + srow) * DT_) + sc;
        float4 sv[8];
        #pragma unroll
        for (int j = 0; j < 8; ++j) sv[j] = src[8 * j];
        #pragma unroll
        for (int j = 0; j < 8; ++j) {
            short4 s;
            s.x = f2bf(sv[j].x); s.y = f2bf(sv[j].y);
            s.z = f2bf(sv[j].z); s.w = f2bf(sv[j].w);
            *(short4*)((char*)A_lds + SWZ(srow, srow * (DT_ * 2) + (sc + 8 * j) * 8)) = s;
        }
    }
    __syncthreads();

    f32x4 acc[5][4];
    #pragma unroll
    for (int ct = 0; ct < 5; ++ct)
        #pragma unroll
        for (int rt = 0; rt < 4; ++rt) acc[ct][rt] = (f32x4){0.f,0.f,0.f,0.f};

    const short* Wbase = Wb + (long)(w * 80 + r16) * DT_ + g * 8;

    bf16x8 aA[4], bA[5], aB[4], bB[5];
    #pragma unroll
    for (int rt = 0; rt < 4; ++rt) {
        const int row = rt * 16 + r16;
        aA[rt] = *(const bf16x8*)((const char*)A_lds + SWZ(row, row * (DT_ * 2) + g * 16));
    }
    #pragma unroll
    for (int ct = 0; ct < 5; ++ct) bA[ct] = *(const bf16x8*)(Wbase + ct * 16 * DT_);

    #pragma unroll
    for (int kc = 0; kc < 8; kc += 2) {
        {   // prefetch kc+1 into B set
            const int kn = kc + 1;
            #pragma unroll
            for (int rt = 0; rt < 4; ++rt) {
                const int row = rt * 16 + r16;
                aB[rt] = *(const bf16x8*)((const char*)A_lds +
                          SWZ(row, row * (DT_ * 2) + kn * 64 + g * 16));
            }
            #pragma unroll
            for (int ct = 0; ct < 5; ++ct)
                bB[ct] = *(const bf16x8*)(Wbase + ct * 16 * DT_ + kn * 32);
        }
        #pragma unroll
        for (int ct = 0; ct < 5; ++ct)
            #pragma unroll
            for (int rt = 0; rt < 4; ++rt)
                acc[ct][rt] = __builtin_amdgcn_mfma_f32_16x16x32_bf16(
                                  aA[rt], bA[ct], acc[ct][rt], 0, 0, 0);
        {   // prefetch kc+2 into A set (clamped address on last iter)
            const int kn = (kc + 2 < 8) ? kc + 2 : 0;
            #pragma unroll
            for (int rt = 0; rt < 4; ++rt) {
                const int row = rt * 16 + r16;
                aA[rt] = *(const bf16x8*)((const char*)A_lds +
                          SWZ(row, row * (DT_ * 2) + kn * 64 + g * 16));
            }
            #pragma unroll
            for (int ct = 0; ct < 5; ++ct)
                bA[ct] = *(const bf16x8*)(Wbase + ct * 16 * DT_ + kn * 32);
        }
        #pragma unroll
        for (int ct = 0; ct < 5; ++ct)
            #pragma unroll
            for (int rt = 0; rt < 4; ++rt)
                acc[ct][rt] = __builtin_amdgcn_mfma_f32_16x16x32_bf16(
                                  aB[rt], bB[ct], acc[ct][rt], 0, 0, 0);
    }

    // C/D: out-col = lane&15 (within col-tile), out-row = (lane>>4)*4 + i
    #pragma unroll
    for (int ct = 0; ct < 5; ++ct) {
        const int col = w * 80 + ct * 16 + r16;
        const float bv = bias[col];
        #pragma unroll
        for (int rt = 0; rt < 4; ++rt)
            #pragma unroll
            for (int i = 0; i < 4; ++i)
                Y[(row0 + rt * 16 + g * 4 + i) * (long)D_ + col] =
                    f2bf(acc[ct][rt][i] + bv);
    }
}

// Fused attention + aggregation, one batch b per block.
// 512 threads = 8 waves: wave = (head-half hh 0..1) x (n-tile wm 0..3).
__global__ __launch_bounds__(512, 2) void attn2(
    const short* __restrict__ Qb, const short* __restrict__ Kb,
    float* __restrict__ aw, float* __restrict__ out_tail)
{
    __shared__ float qn_l[N_];
    __shared__ float qw_l[N_];
    __shared__ float aggp[8][MT_ * 16];
    __shared__ float red2[2];
    const int t = threadIdx.x;
    const int lane = t & 63, w = t >> 6;
    const int wm = w & 3, hh = w >> 2;
    const int r16 = lane & 15, g = lane >> 4;
    const int b = blockIdx.x;

    // --- query-norm softmax weights qw[n] (hh==0 waves only) ---
    if (hh == 0) {
        const short* qrow = Qb + ((long)(b * N_ + wm * 16 + r16)) * D_ + g * 160;
        float ss = 0.f;
        #pragma unroll
        for (int j = 0; j < 20; ++j) {
            bf16x8 v = *(const bf16x8*)(qrow + j * 8);
            #pragma unroll
            for (int e = 0; e < 8; ++e) { float f = bf2f(v[e]); ss += f * f; }
        }
        ss += __shfl_xor(ss, 16);
        ss += __shfl_xor(ss, 32);        // reduce over g (4 k-quarters)
        if (g == 0) qn_l[wm * 16 + r16] = ss;
    }
    __syncthreads();
    if (w == 0) {
        float v = sqrtf(qn_l[lane]);
        float mx = wave_reduce_max(v);
        float e = __expf(v - mx);
        float s = wave_reduce_sum(e);
        qw_l[lane] = e / s;
    }
    __syncthreads();

    float qwr[4];
    #pragma unroll
    for (int i = 0; i < 4; ++i) qwr[i] = qw_l[wm * 16 + g * 4 + i];

    const float inv_scale = 0.0395284707521047f;   // 1/sqrt(640)
    float aggl[MT_];
    #pragma unroll
    for (int mt = 0; mt < MT_; ++mt) aggl[mt] = 0.f;

    for (int hi = 0; hi < 5; ++hi) {
        const int h = hh * 5 + hi;
        const short* qbase = Qb + ((long)(b * N_ + wm * 16 + r16)) * D_ + h * HD_ + g * 8;
        bf16x8 a0 = *(const bf16x8*)(qbase);
        bf16x8 a1 = *(const bf16x8*)(qbase + 32);
        // batch ALL K-fragment loads for this head (one L2 round-trip)
        bf16x8 kb0[MT_], kb1[MT_];
        #pragma unroll
        for (int mt = 0; mt < MT_; ++mt) {
            const short* kbase = Kb + ((long)(b * H_ + mt * 16 + r16)) * D_ + h * HD_ + g * 8;
            kb0[mt] = *(const bf16x8*)(kbase);
            kb1[mt] = *(const bf16x8*)(kbase + 32);
        }
        f32x4 acc[MT_];
        #pragma unroll
        for (int mt = 0; mt < MT_; ++mt) {
            f32x4 z = {0.f,0.f,0.f,0.f};
            z = __builtin_amdgcn_mfma_f32_16x16x32_bf16(a0, kb0[mt], z, 0, 0, 0);
            z = __builtin_amdgcn_mfma_f32_16x16x32_bf16(a1, kb1[mt], z, 0, 0, 0);
            acc[mt] = z;
        }
        // softmax over m for rows n = wm*16 + g*4 + i (lane holds col m = mt*16+r16)
        const bool tailok = (r16 < 8);   // mt==12 valid only for m<200
        float mx[4] = {-INFINITY, -INFINITY, -INFINITY, -INFINITY};
        #pragma unroll
        for (int mt = 0; mt < MT_; ++mt) {
            const bool valid = (mt < 12) || tailok;
            #pragma unroll
            for (int i = 0; i < 4; ++i)
                if (valid) mx[i] = fmaxf(mx[i], acc[mt][i]);
        }
        #pragma unroll
        for (int i = 0; i < 4; ++i) mx[i] = red16_max(mx[i]);
        float sum[4] = {0.f, 0.f, 0.f, 0.f};
        #pragma unroll
        for (int mt = 0; mt < MT_; ++mt) {
            const bool valid = (mt < 12) || tailok;
            #pragma unroll
            for (int i = 0; i < 4; ++i) {
                float e = valid ? __expf((acc[mt][i] - mx[i]) * inv_scale) : 0.f;
                acc[mt][i] = e;
                sum[i] += e;
            }
        }
        float fct[4];
        #pragma unroll
        for (int i = 0; i < 4; ++i) fct[i] = qwr[i] / red16_sum(sum[i]);
        #pragma unroll
        for (int mt = 0; mt < MT_; ++mt)
            aggl[mt] += acc[mt][0] * fct[0] + acc[mt][1] * fct[1]
                      + acc[mt][2] * fct[2] + acc[mt][3] * fct[3];
    }
    // reduce over g (row groups) -> wave partial agg for m = mt*16 + r16
    #pragma unroll
    for (int mt = 0; mt < MT_; ++mt) {
        aggl[mt] += __shfl_xor(aggl[mt], 16);
        aggl[mt] += __shfl_xor(aggl[mt], 32);
    }
    if (g == 0) {
        #pragma unroll
        for (int mt = 0; mt < MT_; ++mt) aggp[w][mt * 16 + r16] = aggl[mt];
    }
    __syncthreads();
    if (t < MT_ * 16) {
        float v = 0.f;
        #pragma unroll
        for (int j = 0; j < 8; ++j) v += aggp[j][t];
        aggp[0][t] = v;
    }
    __syncthreads();
    if (w == 0) {
        float v0 = aggp[0][lane], v1 = aggp[0][lane + 64], v2 = aggp[0][lane + 128];
        const bool has3 = lane < (H_ - 192);
        float v3 = has3 ? aggp[0][lane + 192] : -INFINITY;
        float mx = wave_reduce_max(fmaxf(fmaxf(v0, v1), fmaxf(v2, v3)));
        float s = __expf(v0 - mx) + __expf(v1 - mx) + __expf(v2 - mx)
                + (has3 ? __expf(v3 - mx) : 0.f);
        s = wave_reduce_sum(s);
        if (lane == 0) { red2[0] = mx; red2[1] = s; }
    }
    __syncthreads();
    if (t < H_) {
        float v = __expf(aggp[0][t] - red2[0]) / red2[1];
        aw[b * H_ + t] = v;
        out_tail[b * H_ + t] = v;
    }
}

// gate GEMM + blend + LayerNorm. BM=64, 512 threads, K = 640.
// Wave w owns cols [w*80, w*80+80), all 4 row-tiles; 2-stage register
// pipeline over kc. z written (swizzled) into A_lds after the GEMM.
__global__ __launch_bounds__(512, 2) void out_mfma(
    const float* __restrict__ clicked, const float* __restrict__ aw,
    const short* __restrict__ Wgb, const float* __restrict__ bg,
    const float* __restrict__ gamma, const float* __restrict__ beta,
    float* __restrict__ out)
{
    __shared__ short A_lds[64 * D_];   // 80 KB
    const int t = threadIdx.x;
    const int lane = t & 63, w = t >> 6;
    const int r16 = lane & 15, g = lane >> 4;
    const long row0 = (long)blockIdx.x * 64;

    // stage weighted = aw[row]*clicked[row,:]: one row per 8 threads, batched
    {
        const int srow = t >> 3, sc = t & 7;
        const float a = aw[row0 + srow];
        const float4* src = (const float4*)(clicked + (row0 + srow) * D_) + sc;
        float4 sv[20];
        #pragma unroll
        for (int j = 0; j < 20; ++j) sv[j] = src[8 * j];
        #pragma unroll
        for (int j = 0; j < 20; ++j) {
            short4 s;
            s.x = f2bf(sv[j].x * a); s.y = f2bf(sv[j].y * a);
            s.z = f2bf(sv[j].z * a); s.w = f2bf(sv[j].w * a);
            *(short4*)((char*)A_lds + SWZ(srow, srow * (D_ * 2) + (sc + 8 * j) * 8)) = s;
        }
    }
    __syncthreads();

    f32x4 acc[5][4];
    #pragma unroll
    for (int ct = 0; ct < 5; ++ct)
        #pragma unroll
        for (int rt = 0; rt < 4; ++rt) acc[ct][rt] = (f32x4){0.f,0.f,0.f,0.f};

    const short* Wbase = Wgb + (long)(w * 80 + r16) * D_ + g * 8;

    bf16x8 aA[4], bA[5], aB[4], bB[5];
    #pragma unroll
    for (int rt = 0; rt < 4; ++rt) {
        const int row = rt * 16 + r16;
        aA[rt] = *(const bf16x8*)((const char*)A_lds + SWZ(row, row * (D_ * 2) + g * 16));
    }
    #pragma unroll
    for (int ct = 0; ct < 5; ++ct) bA[ct] = *(const bf16x8*)(Wbase + ct * 16 * D_);

    #pragma unroll
    for (int kc = 0; kc < 20; kc += 2) {
        {   // prefetch kc+1 into B set
            const int kn = kc + 1;
            #pragma unroll
            for (int rt = 0; rt < 4; ++rt) {
                const int row = rt * 16 + r16;
                aB[rt] = *(const bf16x8*)((const char*)A_lds +
                          SWZ(row, row * (D_ * 2) + kn * 64 + g * 16));
            }
            #pragma unroll
            for (int ct = 0; ct < 5; ++ct)
                bB[ct] = *(const bf16x8*)(Wbase + ct * 16 * D_ + kn * 32);
        }
        #pragma unroll
        for (int ct = 0; ct < 5; ++ct)
            #pragma unroll
            for (int rt = 0; rt < 4; ++rt)
                acc[ct][rt] = __builtin_amdgcn_mfma_f32_16x16x32_bf16(
                                  aA[rt], bA[ct], acc[ct][rt], 0, 0, 0);
        {   // prefetch kc+2 into A set (clamped address on last iter)
            const int kn = (kc + 2 < 20) ? kc + 2 : 0;
            #pragma unroll
            for (int rt = 0; rt < 4; ++rt) {
                const int row = rt * 16 + r16;
                aA[rt] = *(const bf16x8*)((const char*)A_lds +
                          SWZ(row, row * (D_ * 2) + kn * 64 + g * 16));
            }
            #pragma unroll
            for (int ct = 0; ct < 5; ++ct)
                bA[ct] = *(const bf16x8*)(Wbase + ct * 16 * D_ + kn * 32);
        }
        #pragma unroll
        for (int ct = 0; ct < 5; ++ct)
            #pragma unroll
            for (int rt = 0; rt < 4; ++rt)
                acc[ct][rt] = __builtin_amdgcn_mfma_f32_16x16x32_bf16(
                                  aB[rt], bB[ct], acc[ct][rt], 0, 0, 0);
    }
    __syncthreads();   // everyone done READING A_lds

    // write z (bf16, swizzled [row][col]) into A_lds
    #pragma unroll
    for (int ct = 0; ct < 5; ++ct) {
        const int col = w * 80 + ct * 16 + r16;
        const float bv = bg[col];
        #pragma unroll
        for (int rt = 0; rt < 4; ++rt)
            #pragma unroll
            for (int i = 0; i < 4; ++i) {
                const int row = rt * 16 + g * 4 + i;
                *(short*)((char*)A_lds + SWZ(row, row * (D_ * 2) + col * 2)) =
                    f2bf(acc[ct][rt][i] + bv);
            }
    }
    __syncthreads();

    // blend + LayerNorm: wave w handles rows w*8 .. w*8+7
    for (int rr = 0; rr < 8; ++rr) {
        const int r = w * 8 + rr;
        const long base = (row0 + r) * (long)D_;
        const float aww = aw[row0 + r];
        float cl[10], ov[10];
        #pragma unroll
        for (int i = 0; i < 10; ++i) cl[i] = clicked[base + lane + 64 * i];
        float s = 0.f, sq = 0.f;
        #pragma unroll
        for (int i = 0; i < 10; ++i) {
            const int c = lane + 64 * i;
            float z = bf2f(*(const short*)((const char*)A_lds +
                           SWZ(r, r * (D_ * 2) + c * 2)));
            float gt = 1.f / (1.f + __expf(-z));
            float o  = gt * (aww * cl[i]) + (1.f - gt) * cl[i];
            ov[i] = o; s += o; sq += o * o;
        }
        s  = wave_reduce_sum(s);
        sq = wave_reduce_sum(sq);
        const float mu  = s * (1.f / D_);
        const float var = sq * (1.f / D_) - mu * mu;
        const float rinv = 1.0f / sqrtf(var + 1e-5f);
        #pragma unroll
        for (int i = 0; i < 10; ++i) {
            const int c = lane + 64 * i;
            out[base + c] = (ov[i] - mu) * rinv * gamma[c] + beta[c];
        }
    }
}

extern "C" void kernel_launch(void* const* d_in, const int* in_sizes, int n_in,
                              void* d_out, int out_size, void* d_ws, size_t ws_size,
                              hipStream_t stream) {
    const float* clicked_news   = (const float*)d_in[0];   // [B,H,D]
    const float* clicked_topics = (const float*)d_in[1];   // [B,H,Dt]
    const float* cand_topics    = (const float*)d_in[2];   // [B,N,Dt]
    const float* Wq = (const float*)d_in[3];
    const float* bq = (const float*)d_in[4];
    const float* Wk = (const float*)d_in[5];
    const float* bk = (const float*)d_in[6];
    // d_in[7], d_in[8] = Wv, bv: dead code w.r.t. outputs
    const float* Wg = (const float*)d_in[9];
    const float* bg = (const float*)d_in[10];
    const float* ln_gamma = (const float*)d_in[11];
    const float* ln_beta  = (const float*)d_in[12];

    float* out = (float*)d_out;
    float* ws  = (float*)d_ws;

    // ws layout: aw (f32), then bf16 arrays
    float* aw = ws;                                     // B*H floats
    short* sbase = (short*)(ws + (long)B_ * H_);
    short* Qb   = sbase;                                // B*N*D  = 10,485,760
    short* Wq_b = Qb + (long)B_ * N_ * D_;              // 163,840
    short* Wg_b = Wq_b + (long)D_ * DT_;                // 409,600
    short* Wk_b = Wg_b + (long)D_ * D_;                 // 163,840
    // Kb (bf16) lives at the start of d_out: read by attn2, then overwritten
    // by out_mfma's final output. Padded by 8 rows for the mt=12 tail reads.
    short* Kb = (short*)d_out;                          // (B*H + 8) * D_ shorts
    float* out_tail = out + (long)B_ * H_ * D_;         // attn_weights_agg

    convert_w<<<128, 256, 0, stream>>>(Wq, Wq_b, D_ * DT_);
    convert_w<<<128, 256, 0, stream>>>(Wk, Wk_b, D_ * DT_);
    convert_w<<<256, 256, 0, stream>>>(Wg, Wg_b, D_ * D_);

    proj_mfma<<<(B_ * N_) / 64, 512, 0, stream>>>(cand_topics, Wq_b, bq, Qb);
    proj_mfma<<<(B_ * H_) / 64, 512, 0, stream>>>(clicked_topics, Wk_b, bk, Kb);
    attn2<<<B_, 512, 0, stream>>>(Qb, Kb, aw, out_tail);
    out_mfma<<<(B_ * H_) / 64, 512, 0, stream>>>(clicked_news, aw, Wg_b, bg,
                                                 ln_gamma, ln_beta, out);
}